// Round 1
// baseline (493.835 us; speedup 1.0000x reference)
//
#include <hip/hip_runtime.h>

#define NSTR_MAX 512

// Inputs: coords [N,3] f32, shape_params [S,4] f32 (cx,cy,cz,r),
//         color_params [S,3] f32, alpha_params [S,1] f32
// Output (flat concat): density [N], rgb [N,3], c [N,3]  -> 7N floats

__global__ __launch_bounds__(256) void stroke_field_kernel(
    const float* __restrict__ coords,
    const float* __restrict__ shape,
    const float* __restrict__ color,
    const float* __restrict__ alpha,
    float* __restrict__ out,
    int n, int ns)
{
    // Stage stroke params in LDS: per stroke two float4s:
    //   a = (cx, cy, cz, 5*r + 0.5)   [t = clamp(fma(-5,dist,a.w),0,1)]
    //   b = (cr, cg, cb, max(alpha,0)*50)
    __shared__ float4 sd[2 * NSTR_MAX];
    for (int s = threadIdx.x; s < ns; s += blockDim.x) {
        float4 sp = ((const float4*)shape)[s];
        sp.w = fmaf(5.0f, sp.w, 0.5f);
        sd[2 * s] = sp;
        float dp = fmaxf(alpha[s], 0.0f) * 50.0f;
        sd[2 * s + 1] = make_float4(color[3 * s], color[3 * s + 1], color[3 * s + 2], dp);
    }
    __syncthreads();

    int i = blockIdx.x * blockDim.x + threadIdx.x;
    if (i >= n) return;

    float x = coords[3 * i + 0];
    float y = coords[3 * i + 1];
    float z = coords[3 * i + 2];

    // contract(x)/2 : identity/2 inside unit ball, (2 - 1/n)*(x/n)/2 outside
    float n2 = fmaf(x, x, fmaf(y, y, z * z));
    float nn = fmaxf(__builtin_amdgcn_sqrtf(n2), 1e-9f);
    float invn = 1.0f / nn;
    float sc_out = (2.0f - invn) * (0.5f * invn);
    float sc = (nn <= 1.0f) ? 0.5f : sc_out;
    float cx = x * sc, cy = y * sc, cz = z * sc;

    float hd = 0.0f, hr = 0.0f, hg = 0.0f, hb = 0.0f, hw = 1.0f;

#pragma unroll 4
    for (int s = 0; s < ns; ++s) {
        float4 a = sd[2 * s];
        float4 b = sd[2 * s + 1];
        float dx = cx - a.x;
        float dy = cy - a.y;
        float dz = cz - a.z;
        float d2 = fmaf(dx, dx, fmaf(dy, dy, dz * dz));
        float dist = __builtin_amdgcn_sqrtf(d2);
        // t = (clip(r - dist, -0.1, 0.1)/0.1 + 1) * 0.5 == clamp(5*(r-dist)+0.5, 0, 1)
        float t = fmaf(-5.0f, dist, a.w);
        t = fminf(fmaxf(t, 0.0f), 1.0f);   // v_med3_f32
        float omt = 1.0f - t;
        hd = fmaf(omt, hd, t * b.w);
        hr = fmaf(omt, hr, t * b.x);
        hg = fmaf(omt, hg, t * b.y);
        hb = fmaf(omt, hb, t * b.z);
        hw = omt * hw;
    }

    float inv = 1.0f / (1.0f + 1e-6f - hw);
    float r = fminf(fmaxf(hr * inv, 0.0f), 1.0f);
    float g = fminf(fmaxf(hg * inv, 0.0f), 1.0f);
    float b_ = fminf(fmaxf(hb * inv, 0.0f), 1.0f);

    out[i] = hd;
    float* rgb = out + n;
    rgb[3 * i + 0] = r;
    rgb[3 * i + 1] = g;
    rgb[3 * i + 2] = b_;
    float* cw = out + 4 * (size_t)n;
    cw[3 * i + 0] = cx;
    cw[3 * i + 1] = cy;
    cw[3 * i + 2] = cz;
}

extern "C" void kernel_launch(void* const* d_in, const int* in_sizes, int n_in,
                              void* d_out, int out_size, void* d_ws, size_t ws_size,
                              hipStream_t stream) {
    const float* coords = (const float*)d_in[0];
    const float* shape  = (const float*)d_in[1];
    const float* color  = (const float*)d_in[2];
    const float* alpha  = (const float*)d_in[3];
    float* out = (float*)d_out;

    int n  = in_sizes[0] / 3;
    int ns = in_sizes[1] / 4;

    int block = 256;
    int grid = (n + block - 1) / block;
    stroke_field_kernel<<<grid, block, 0, stream>>>(coords, shape, color, alpha, out, n, ns);
}